// Round 2
// baseline (1029.353 us; speedup 1.0000x reference)
//
#include <hip/hip_runtime.h>

// sign(tanh(conv1x1(x,W))) == sign(x @ W)
// x: [M=131072, K=512] f32, W: [K=512, N=32] f32, out: [M,N] f32 in {-1,0,1}
//
// f32 register-tiled GEMM (4 rows x 4 cols / thread), double-buffered LDS
// chunks staged with global_load_lds (width 16). x tile is XOR-swizzled via
// pre-swizzled GLOBAL source + swizzled ds_read (LDS dest stays linear).
// |acc| < TAU is recomputed in f64 wave-cooperatively -> exact sign.

constexpr int K     = 512;
constexpr int N     = 32;
constexpr int BROWS = 128;           // rows per block -> 1024 blocks = 4/CU
constexpr int KC    = 32;            // k-chunk (128 B per row-chunk)
constexpr float TAU = 1e-3f;         // worst-case f32 dot error ~3e-4

#define GLOAD_LDS16(g, s) __builtin_amdgcn_global_load_lds(              \
    (const __attribute__((address_space(1))) void*)(g),                  \
    (__attribute__((address_space(3))) void*)(s), 16, 0, 0)

__global__ __launch_bounds__(256, 4)   // 4 waves/EU -> 4 blocks/CU (LDS=40KiB binds too)
void conv_sign_kernel(const float* __restrict__ x,
                      const float* __restrict__ Wm,
                      float* __restrict__ out)
{
    __shared__ float xs[2 * BROWS * KC];   // 2 x 16 KiB
    __shared__ float ws[2 * KC * N];       // 2 x  4 KiB

    const int t  = threadIdx.x;
    const int w  = t >> 6;                 // wave id (uniform per wave)
    const int l  = t & 63;                 // lane
    const int block_row = blockIdx.x * BROWS;

    const int r0    = (t >> 3) * 4;        // 4 consecutive rows per thread
    const int c0    = (t & 7) * 4;         // 4 consecutive cols per thread
    const int sread = (r0 >> 2) & 7;       // swizzle key, constant for r0..r0+3

    float acc[4][4];
#pragma unroll
    for (int i = 0; i < 4; ++i)
#pragma unroll
        for (int j = 0; j < 4; ++j) acc[i][j] = 0.f;

    // ---- staging: 4x global_load_lds for x (8 rows/wave/issue) + 1 for W ----
    // LDS slot (row, c4) holds global 16B-unit (c4 ^ ((row>>2)&7)) of that row.
    // Dest is wave-uniform base + lane*16 (linear); swizzle lives in the
    // per-lane GLOBAL address (rule: both-sides-or-neither).
    auto stage = [&](int buf, int kc) {
#pragma unroll
        for (int p = 0; p < 4; ++p) {
            const int lr   = p * 32 + w * 8 + (l >> 3);          // local row
            const int gcol = kc + (((l & 7) ^ ((lr >> 2) & 7)) << 2);
            const float* gp = x + (size_t)(block_row + lr) * K + gcol;
            float* lp = xs + buf * (BROWS * KC) + p * 1024 + w * 256; // uniform
            GLOAD_LDS16(gp, lp);
        }
        const float* gw = Wm + kc * N + w * 256 + l * 4;
        float* lw = ws + buf * (KC * N) + w * 256;               // uniform
        GLOAD_LDS16(gw, lw);
    };

    stage(0, 0);
    __syncthreads();                       // drains vmcnt(0): buf0 ready

    const int NCHUNK = K / KC;             // 16
    for (int tc = 0; tc < NCHUNK; ++tc) {
        const int cur = tc & 1;
        if (tc + 1 < NCHUNK) stage(cur ^ 1, (tc + 1) * KC);  // prefetch

        const float* xb = xs + cur * (BROWS * KC) + r0 * KC;
        const float* wb = ws + cur * (KC * N) + c0;
#pragma unroll
        for (int k4 = 0; k4 < KC / 4; ++k4) {
            const int sl = (k4 ^ sread) << 2;      // swizzled 16B slot
            float4 xv[4], wv[4];
#pragma unroll
            for (int i = 0; i < 4; ++i)
                xv[i] = *reinterpret_cast<const float4*>(xb + i * KC + sl);
#pragma unroll
            for (int j = 0; j < 4; ++j)
                wv[j] = *reinterpret_cast<const float4*>(wb + (k4 * 4 + j) * N);
#pragma unroll
            for (int i = 0; i < 4; ++i) {
#pragma unroll
                for (int j = 0; j < 4; ++j) {
                    const float xr = (&xv[i].x)[j];
                    acc[i][0] += xr * wv[j].x;
                    acc[i][1] += xr * wv[j].y;
                    acc[i][2] += xr * wv[j].z;
                    acc[i][3] += xr * wv[j].w;
                }
            }
        }
        if (tc + 1 < NCHUNK) __syncthreads();  // compute(cur) done + next buf ready
    }

    // ---- exact f64 fixup for ambiguous accumulators ----
#pragma unroll
    for (int ai = 0; ai < 4; ++ai) {
#pragma unroll
        for (int bi = 0; bi < 4; ++bi) {
            unsigned long long bal = __ballot(fabsf(acc[ai][bi]) < TAU);
            while (bal) {
                const int s = __ffsll(bal) - 1;
                bal &= bal - 1;
                const int gr = block_row + w * 32 + ((s >> 3) << 2) + ai;
                const int gc = ((s & 7) << 2) + bi;
                const float* xr = x  + (size_t)gr * K + l * 8;
                const float* wr = Wm + (size_t)(l * 8) * N + gc;
                double part = 0.0;
#pragma unroll
                for (int q = 0; q < 8; ++q)
                    part += (double)xr[q] * (double)wr[q * N];
#pragma unroll
                for (int off = 32; off > 0; off >>= 1)
                    part += __shfl_xor(part, off);
                if (l == s)
                    acc[ai][bi] = (part > 0.0) ? 2.f : ((part < 0.0) ? -2.f : 0.f);
            }
        }
    }

    // ---- sign + store: lane's 8 col-neighbors cover a full 128B row ----
#pragma unroll
    for (int i = 0; i < 4; ++i) {
        const int gr = block_row + r0 + i;
        float4 o;
        o.x = (acc[i][0] > 0.f) ? 1.f : ((acc[i][0] < 0.f) ? -1.f : 0.f);
        o.y = (acc[i][1] > 0.f) ? 1.f : ((acc[i][1] < 0.f) ? -1.f : 0.f);
        o.z = (acc[i][2] > 0.f) ? 1.f : ((acc[i][2] < 0.f) ? -1.f : 0.f);
        o.w = (acc[i][3] > 0.f) ? 1.f : ((acc[i][3] < 0.f) ? -1.f : 0.f);
        *reinterpret_cast<float4*>(out + (size_t)gr * N + c0) = o;
    }
}

extern "C" void kernel_launch(void* const* d_in, const int* in_sizes, int n_in,
                              void* d_out, int out_size, void* d_ws, size_t ws_size,
                              hipStream_t stream)
{
    const float* x  = (const float*)d_in[0];
    const float* Wm = (const float*)d_in[1];
    float* out      = (float*)d_out;
    const int M     = in_sizes[0] / K;            // 131072
    const int grid  = M / BROWS;                  // 1024
    hipLaunchKernelGGL(conv_sign_kernel, dim3(grid), dim3(256), 0, stream,
                       x, Wm, out);
}

// Round 3
// 148.297 us; speedup vs baseline: 6.9411x; 6.9411x over previous
//
#include <hip/hip_runtime.h>

// sign(tanh(conv1x1(x,W))) == sign(x @ W)
// x: [M=131072, K=512] f32, W: [K=512, N=32] f32, out: [M,N] f32 in {-1,0,1}
//
// LDS-free register-tiled GEMM: 4 rows x 4 cols per thread. The 8 col-group
// lanes of a wave share each x row-segment address (HW broadcast), so x is
// fetched from HBM exactly once; 64B-line remainders are reused across the
// next 3 k4 iterations from L1/L2. W (64 KB) stays hot in L1/L2.
// |acc| < TAU is recomputed in f64 wave-cooperatively -> exact sign.
//
// Round-2 lesson (journal): global_load_lds with XOR-permuted per-lane
// source addresses caused 6x read / 156x write HBM amplification. Avoid.

constexpr int K     = 512;
constexpr int N     = 32;
constexpr int BROWS = 128;           // rows per block -> grid 1024 = 4 blocks/CU
constexpr float TAU = 1e-3f;         // worst-case f32 dot error ~3e-4

__global__ __launch_bounds__(256)
void conv_sign_kernel(const float* __restrict__ x,
                      const float* __restrict__ Wm,
                      float* __restrict__ out)
{
    const int t = threadIdx.x;
    const int l = t & 63;
    const int w = t >> 6;
    const int block_row = blockIdx.x * BROWS;

    const int r0 = (t >> 3) << 2;    // local row base: 32 groups x 4 rows = 128
    const int c0 = (t & 7) << 2;     // col base: 8 groups x 4 cols = 32

    const float* xp = x + (size_t)(block_row + r0) * K;

    float acc[4][4];
#pragma unroll
    for (int i = 0; i < 4; ++i)
#pragma unroll
        for (int j = 0; j < 4; ++j) acc[i][j] = 0.f;

#pragma unroll 8
    for (int k4 = 0; k4 < K / 4; ++k4) {
        float4 xv[4], wv[4];
#pragma unroll
        for (int i = 0; i < 4; ++i)
            xv[i] = *reinterpret_cast<const float4*>(xp + (size_t)i * K + k4 * 4);
#pragma unroll
        for (int j = 0; j < 4; ++j)
            wv[j] = *reinterpret_cast<const float4*>(Wm + (k4 * 4 + j) * N + c0);
#pragma unroll
        for (int i = 0; i < 4; ++i) {
#pragma unroll
            for (int j = 0; j < 4; ++j) {
                const float xk = (&xv[i].x)[j];
                acc[i][0] += xk * wv[j].x;
                acc[i][1] += xk * wv[j].y;
                acc[i][2] += xk * wv[j].z;
                acc[i][3] += xk * wv[j].w;
            }
        }
    }

    // ---- exact f64 fixup for ambiguous accumulators (rare: ~1e-3 rate) ----
#pragma unroll
    for (int ai = 0; ai < 4; ++ai) {
#pragma unroll
        for (int bi = 0; bi < 4; ++bi) {
            unsigned long long bal = __ballot(fabsf(acc[ai][bi]) < TAU);
            while (bal) {
                const int s = __ffsll(bal) - 1;
                bal &= bal - 1;
                const int gr = block_row + 32 * w + ((s >> 3) << 2) + ai;
                const int gc = ((s & 7) << 2) + bi;
                const float* xr = x  + (size_t)gr * K + l * 8;
                const float* wr = Wm + (size_t)(l * 8) * N + gc;
                double part = 0.0;
#pragma unroll
                for (int q = 0; q < 8; ++q)
                    part += (double)xr[q] * (double)wr[q * N];
#pragma unroll
                for (int off = 32; off > 0; off >>= 1)
                    part += __shfl_xor(part, off);
                if (l == s)
                    acc[ai][bi] = (part > 0.0) ? 2.f : ((part < 0.0) ? -2.f : 0.f);
            }
        }
    }

    // ---- sign + store: 8 col-lanes cover a full 128B output row ----
#pragma unroll
    for (int i = 0; i < 4; ++i) {
        const int gr = block_row + r0 + i;
        float4 o;
        o.x = (acc[i][0] > 0.f) ? 1.f : ((acc[i][0] < 0.f) ? -1.f : 0.f);
        o.y = (acc[i][1] > 0.f) ? 1.f : ((acc[i][1] < 0.f) ? -1.f : 0.f);
        o.z = (acc[i][2] > 0.f) ? 1.f : ((acc[i][2] < 0.f) ? -1.f : 0.f);
        o.w = (acc[i][3] > 0.f) ? 1.f : ((acc[i][3] < 0.f) ? -1.f : 0.f);
        *reinterpret_cast<float4*>(out + (size_t)gr * N + c0) = o;
    }
}

extern "C" void kernel_launch(void* const* d_in, const int* in_sizes, int n_in,
                              void* d_out, int out_size, void* d_ws, size_t ws_size,
                              hipStream_t stream)
{
    const float* x  = (const float*)d_in[0];
    const float* Wm = (const float*)d_in[1];
    float* out      = (float*)d_out;
    const int M     = in_sizes[0] / K;            // 131072
    const int grid  = M / BROWS;                  // 1024
    hipLaunchKernelGGL(conv_sign_kernel, dim3(grid), dim3(256), 0, stream,
                       x, Wm, out);
}